// Round 13
// baseline (560.006 us; speedup 1.0000x reference)
//
#include <hip/hip_runtime.h>
#include <hip/hip_bf16.h>

#define NN 50000   // nodes
#define EE 800000  // directed edges (no self loops)
#define ET 850000  // EE + NN self loops
#define GG 1024    // graphs
#define DD 128     // embedding dim
#define HH 4       // heads
#define LL 3       // layers
#define ND 78      // node feature dim
#define HD 512     // HH*DD
#define K1P 96     // node-dim padded to multiple of 32 for MFMA
#define SLOPE 0.2f
#define EPSV 1e-16f
#define SB 196     // scan blocks = ceil(NN/256)
#define PADS 520   // LDS row stride in shorts (512 + 8 pad)

typedef __hip_bfloat16 bf16;
typedef __attribute__((ext_vector_type(8))) unsigned short u16x8;
typedef __attribute__((ext_vector_type(8))) short s16x8;   // MFMA A/B fragment (8 bf16)
typedef __attribute__((ext_vector_type(4))) float f32x4;   // MFMA C/D fragment
typedef __attribute__((ext_vector_type(2))) float f32x2;   // packed fp32 (v_pk_fma_f32)

__device__ __forceinline__ float b2f(bf16 v) { return __bfloat162float(v); }
__device__ __forceinline__ bf16 f2b(float v) { return __float2bfloat16(v); }
__device__ __forceinline__ float bu2f(unsigned short u) {
    return __uint_as_float(((unsigned)u) << 16);
}
__device__ __forceinline__ unsigned short f2bu(float f) {
    unsigned u = __float_as_uint(f);
    unsigned rounded = u + 0x7FFFu + ((u >> 16) & 1u);
    return (unsigned short)(rounded >> 16);
}
__device__ __forceinline__ float lrelu(float e) { return (e > 0.f) ? e : SLOPE * e; }

// ---------------- fused preprocessing (region-dispatched) ----------------
// R0 xconv | R1 nw_conv | R2 wt2_conv | R3 gw_conv | R4 asd_w | R5 pool_init | R6 deg_init
#define PRE0 (NN * K1P)                    // 4,800,000
#define PRE1 (PRE0 + DD * K1P + DD * DD)   // + 28,672
#define PRE2 (PRE1 + LL * DD * HD)         // + 196,608
#define PRE3 (PRE2 + 2 * 1024 * DD)        // + 262,144
#define PRE4 (PRE3 + LL * DD * HH)         // + 1,536
#define PRE5 (PRE4 + GG * DD + GG)         // + 132,096
#define PRE6 (PRE5 + NN)                   // + 50,000 -> 5,471,056 total
__global__ void prep_misc(const float* __restrict__ x, const float* __restrict__ W1,
                          const float* __restrict__ W2, const float* __restrict__ lin_w,
                          const float* __restrict__ att_src, const float* __restrict__ att_dst,
                          const float* __restrict__ gW1, const float* __restrict__ gW2,
                          bf16* __restrict__ xb, bf16* __restrict__ W1t, bf16* __restrict__ W2t,
                          bf16* __restrict__ Bt, float* __restrict__ ws, float* __restrict__ wd,
                          bf16* __restrict__ gW1t, bf16* __restrict__ gW2t,
                          float* __restrict__ pooled, int* __restrict__ counts,
                          int* __restrict__ deg) {
    int idx = blockIdx.x * 256 + threadIdx.x;
    if (idx < PRE0) {                       // xconv: x -> bf16 zero-padded to K1P
        int n = idx / K1P;
        int k = idx % K1P;
        xb[idx] = f2b((k < ND) ? x[(size_t)n * ND + k] : 0.f);
        return;
    }
    if (idx < PRE1) {                       // nw_conv
        idx -= PRE0;
        if (idx < DD * K1P) {
            int c = idx / K1P, k = idx % K1P;
            W1t[idx] = f2b((k < ND) ? W1[(size_t)k * DD + c] : 0.f);
        } else {
            idx -= DD * K1P;
            int c = idx / DD, k = idx % DD;
            W2t[idx] = f2b(W2[(size_t)k * DD + c]);
        }
        return;
    }
    if (idx < PRE2) {                       // wt2_conv: Bt[l][c][k=h*128+d]
        idx -= PRE1;
        int l = idx / (DD * HD);
        int rem = idx % (DD * HD);
        int c = rem / HD;
        int k = rem % HD;
        int h = k >> 7;
        int d = k & 127;
        Bt[idx] = f2b(lin_w[((size_t)(l * DD + d) * HH + h) * DD + c]);
        return;
    }
    if (idx < PRE3) {                       // gw_conv
        idx -= PRE2;
        if (idx < 1024 * DD) {
            int c = idx / DD, k = idx % DD;
            gW1t[idx] = f2b(gW1[(size_t)k * 1024 + c]);
        } else {
            idx -= 1024 * DD;
            int c = idx / 1024, k = idx % 1024;
            gW2t[idx] = f2b(gW2[(size_t)k * DD + c]);
        }
        return;
    }
    if (idx < PRE4) {                       // asd_w: ws/wd [L][D][H]
        idx -= PRE3;
        int l = idx / (DD * HH);
        int rem = idx % (DD * HH);
        int d = rem >> 2;
        int h = rem & 3;
        const float* wrow = lin_w + ((size_t)(l * DD + d) * HH + h) * DD;
        const float* as = att_src + (size_t)(l * HH + h) * DD;
        const float* ad = att_dst + (size_t)(l * HH + h) * DD;
        float s1 = 0.f, s2 = 0.f;
        for (int e = 0; e < DD; e++) { float w = wrow[e]; s1 += w * as[e]; s2 += w * ad[e]; }
        ws[idx] = s1;
        wd[idx] = s2;
        return;
    }
    if (idx < PRE5) {                       // pool_init (counts/pooled zero BEFORE conv_batch atomics)
        idx -= PRE4;
        if (idx < GG * DD) pooled[idx] = 0.f;
        if (idx < GG) counts[idx] = 0;
        return;
    }
    if (idx < PRE6) {                       // deg init (self loop = 1) BEFORE conv_edges atomics
        deg[idx - PRE5] = 1;
    }
}

// ---------------- edge conversion: inline int-width detect + dst histogram ----------------
__global__ void conv_edges(const void* __restrict__ src, int* __restrict__ dst,
                           int* __restrict__ deg) {
    __shared__ int z;
    int t = threadIdx.x;
    const unsigned* w = (const unsigned*)src;
    if (t == 0) z = 0;
    __syncthreads();
    if (w[2 * t + 1] == 0u) atomicAdd(&z, 1);   // high dwords zero -> int64
    __syncthreads();
    int flag = (z >= 200) ? 1 : 0;
    int i = blockIdx.x * 256 + t;
    if (i >= 2 * EE) return;
    const int* s = (const int*)src;
    int g = flag ? s[2 * i] : s[i];
    dst[i] = g;
    if (i >= EE && (unsigned)g < NN) atomicAdd(&deg[g], 1);   // dst histogram
}

// ---------------- batch conversion: inline detect + per-graph counts ----------------
__global__ void conv_batch(const void* __restrict__ src, int* __restrict__ dst,
                           int* __restrict__ counts) {
    __shared__ int z;
    int t = threadIdx.x;
    const unsigned* w = (const unsigned*)src;
    if (t == 0) z = 0;
    __syncthreads();
    if (w[2 * t + 1] == 0u) atomicAdd(&z, 1);
    __syncthreads();
    int flag = (z >= 200) ? 1 : 0;
    int i = blockIdx.x * 256 + t;
    if (i >= NN) return;
    const int* s = (const int*)src;
    int g = flag ? s[2 * i] : s[i];
    dst[i] = g;
    if ((unsigned)g < GG) atomicAdd(&counts[g], 1);
}

// ---------------- FUSED node MLP: h = relu(xb@W1t^T+b1)@W2t^T+b2, + layer-0 a_s/a_d ----------------
__global__ __launch_bounds__(256) void mlp_fused(const bf16* __restrict__ xb,
                                                 const bf16* __restrict__ W1t,
                                                 const float* __restrict__ b1,
                                                 const bf16* __restrict__ W2t,
                                                 const float* __restrict__ b2,
                                                 const float* __restrict__ ws0,
                                                 const float* __restrict__ wd0,
                                                 bf16* __restrict__ h,
                                                 float* __restrict__ a_s, float* __restrict__ a_d) {
    __shared__ __align__(16) short tsl[4][16][136];   // per-wave ts tile; 136-short stride
    int wv4 = threadIdx.x >> 6;
    int wid = (blockIdx.x * 256 + threadIdx.x) >> 6;
    if (wid >= NN / 16) return;            // no barriers in kernel -> early exit safe
    int lane = threadIdx.x & 63;
    int r16 = lane & 15;
    int q = lane >> 4;

    // ---- phase A: ts = relu(xb @ W1t^T + b1) -> LDS ----
    {
        const short* ab = (const short*)xb;
        const short* bb = (const short*)W1t;
        int arow = wid * 16 + r16;
        s16x8 afr[3];
#pragma unroll
        for (int c = 0; c < 3; c++) afr[c] = *(const s16x8*)(ab + (size_t)arow * K1P + c * 32 + q * 8);
#pragma unroll
        for (int nt = 0; nt < 8; nt++) {
            int brow = nt * 16 + r16;
            f32x4 acc = {0.f, 0.f, 0.f, 0.f};
#pragma unroll
            for (int c = 0; c < 3; c++) {
                s16x8 b = *(const s16x8*)(bb + (size_t)brow * K1P + c * 32 + q * 8);
                acc = __builtin_amdgcn_mfma_f32_16x16x32_bf16(afr[c], b, acc, 0, 0, 0);
            }
            int cc = nt * 16 + r16;
            float bias = b1[cc];
#pragma unroll
            for (int r = 0; r < 4; r++)
                tsl[wv4][q * 4 + r][cc] = (short)f2bu(fmaxf(acc[r] + bias, 0.f));
        }
    }

    // ---- phase B: h = ts @ W2t^T + b2 (A from LDS), + a_s/a_d partials ----
    {
        const short* bb = (const short*)W2t;
        s16x8 afr[4];
#pragma unroll
        for (int c = 0; c < 4; c++)
            afr[c] = *(const s16x8*)(&tsl[wv4][r16][c * 32 + q * 8]);
        float part[4][8];
#pragma unroll
        for (int r = 0; r < 4; r++)
#pragma unroll
            for (int k = 0; k < 8; k++) part[r][k] = 0.f;
#pragma unroll
        for (int nt = 0; nt < 8; nt++) {
            int brow = nt * 16 + r16;
            f32x4 acc = {0.f, 0.f, 0.f, 0.f};
#pragma unroll
            for (int c = 0; c < 4; c++) {
                s16x8 b = *(const s16x8*)(bb + (size_t)brow * DD + c * 32 + q * 8);
                acc = __builtin_amdgcn_mfma_f32_16x16x32_bf16(afr[c], b, acc, 0, 0, 0);
            }
            int cc = nt * 16 + r16;
            float bias = b2[cc];
            float4 w4s = *(const float4*)(ws0 + cc * 4);
            float4 w4d = *(const float4*)(wd0 + cc * 4);
#pragma unroll
            for (int r = 0; r < 4; r++) {
                unsigned short us = f2bu(acc[r] + bias);
                int row = wid * 16 + q * 4 + r;
                ((unsigned short*)h)[(size_t)row * DD + cc] = us;
                float v = bu2f(us);   // use ROUNDED value (matches a_sd2-from-bf16 path)
                part[r][0] += v * w4s.x; part[r][1] += v * w4s.y;
                part[r][2] += v * w4s.z; part[r][3] += v * w4s.w;
                part[r][4] += v * w4d.x; part[r][5] += v * w4d.y;
                part[r][6] += v * w4d.z; part[r][7] += v * w4d.w;
            }
        }
#pragma unroll
        for (int r = 0; r < 4; r++)
#pragma unroll
            for (int k = 0; k < 8; k++) {
                float v = part[r][k];
                v += __shfl_xor(v, 1); v += __shfl_xor(v, 2);
                v += __shfl_xor(v, 4); v += __shfl_xor(v, 8);
                part[r][k] = v;
            }
        if (r16 == 0) {
#pragma unroll
            for (int r = 0; r < 4; r++) {
                int row = wid * 16 + q * 4 + r;
                *(float4*)(a_s + (size_t)row * 4) =
                    make_float4(part[r][0], part[r][1], part[r][2], part[r][3]);
                *(float4*)(a_d + (size_t)row * 4) =
                    make_float4(part[r][4], part[r][5], part[r][6], part[r][7]);
            }
        }
    }
}

// ---------------- a_s,a_d from h (layers 1,2): one thread per node ----------------
__global__ __launch_bounds__(256) void a_sd2(const bf16* __restrict__ h,
                                             const float* __restrict__ ws,
                                             const float* __restrict__ wd,
                                             float* __restrict__ a_s, float* __restrict__ a_d) {
    __shared__ float wsl[DD][HH];
    __shared__ float wdl[DD][HH];
    int t = threadIdx.x;
    for (int i = t; i < DD * HH; i += 256) { wsl[i >> 2][i & 3] = ws[i]; wdl[i >> 2][i & 3] = wd[i]; }
    __syncthreads();
    int n = blockIdx.x * 256 + t;
    if (n >= NN) return;
    const u16x8* row = (const u16x8*)((const unsigned short*)h + (size_t)n * DD);
    float s1[HH] = {0.f, 0.f, 0.f, 0.f};
    float s2[HH] = {0.f, 0.f, 0.f, 0.f};
    for (int c = 0; c < 16; c++) {
        u16x8 v = row[c];
#pragma unroll
        for (int k = 0; k < 8; k++) {
            int d = c * 8 + k;
            float f = bu2f(v[k]);
#pragma unroll
            for (int hh = 0; hh < HH; hh++) {
                s1[hh] += f * wsl[d][hh];
                s2[hh] += f * wdl[d][hh];
            }
        }
    }
#pragma unroll
    for (int hh = 0; hh < HH; hh++) {
        a_s[n * HH + hh] = s1[hh];
        a_d[n * HH + hh] = s2[hh];
    }
}

// ---------------- counting sort scan ----------------
__global__ __launch_bounds__(256) void block_sums(const int* __restrict__ deg, int* __restrict__ bsum) {
    __shared__ int part[256];
    int t = threadIdx.x;
    int i = blockIdx.x * 256 + t;
    part[t] = (i < NN) ? deg[i] : 0;
    __syncthreads();
    for (int off = 128; off > 0; off >>= 1) {
        if (t < off) part[t] += part[t + off];
        __syncthreads();
    }
    if (t == 0) bsum[blockIdx.x] = part[0];
}
__global__ __launch_bounds__(256) void scan_bsum(const int* __restrict__ bsum, int* __restrict__ boff,
                                                 int* __restrict__ start) {
    __shared__ int part[256];
    int t = threadIdx.x;
    part[t] = (t < SB) ? bsum[t] : 0;
    __syncthreads();
    for (int off = 1; off < 256; off <<= 1) {
        int add = (t >= off) ? part[t - off] : 0;
        __syncthreads();
        part[t] += add;
        __syncthreads();
    }
    if (t < SB) boff[t] = (t == 0) ? 0 : part[t - 1];
    if (t == 255) start[NN] = part[SB - 1];
}
__global__ __launch_bounds__(256) void scan_final(const int* __restrict__ deg, const int* __restrict__ boff,
                                                  int* __restrict__ start, int* __restrict__ cursor) {
    __shared__ int part[256];
    int t = threadIdx.x;
    int i = blockIdx.x * 256 + t;
    int v = (i < NN) ? deg[i] : 0;
    part[t] = v;
    __syncthreads();
    for (int off = 1; off < 256; off <<= 1) {
        int add = (t >= off) ? part[t - off] : 0;
        __syncthreads();
        part[t] += add;
        __syncthreads();
    }
    if (i < NN) {
        int ex = boff[blockIdx.x] + part[t] - v;
        start[i] = ex;
        cursor[i] = ex;
    }
}
__global__ void scatter_all(const int* __restrict__ ei, int* cursor, int* ssrc) {
    int i = blockIdx.x * 256 + threadIdx.x;
    if (i < NN) {
        int pos = atomicAdd(&cursor[i], 1);
        if ((unsigned)pos < ET) ssrc[pos] = i;
        return;
    }
    int e = i - NN;
    if (e >= EE) return;
    int src = ei[e];
    int dst = ei[EE + e];
    if ((unsigned)dst >= NN) return;
    int pos = atomicAdd(&cursor[dst], 1);
    if ((unsigned)pos < ET) ssrc[pos] = ((unsigned)src < NN) ? src : 0;
}

// ---------------- FUSED: edge softmax + aggregate 16 nodes + post-GEMM (MFMA) ----------------
// Pass 2 now uses ASM-FORCED pipelining: R8's source-level ping-pong was defeated by
// the compiler (loads re-sunk to use sites; VGPR stayed 32, dur unchanged). Per-block
// lifetime (~15.6us) matches the fully-SERIALIZED ~13 gathers x ~1us latency estimate
// -> effective 1 load in flight. Fix per AITER/HK pattern: inline-asm
// global_load_dwordx2 into named uint64 regs + counted s_waitcnt vmcnt(4) (never 0
// mid-loop), registers tied "+v" to the waitcnt + sched_barrier(0) so consumers can't
// hoist (rule-18). Two named 4-load chunks in flight = 8 outstanding loads/wave.
__global__ __launch_bounds__(1024, 8) void agg_gemm(const int* __restrict__ start,
                                                    const int* __restrict__ ssrc,
                                                    const float* __restrict__ a_s,
                                                    const float* __restrict__ a_d,
                                                    const bf16* __restrict__ h,
                                                    const bf16* __restrict__ Bt,
                                                    const float* __restrict__ conv_b,
                                                    bf16* __restrict__ hnext) {
    __shared__ short aggL[16 * PADS];      // 16 rows x 512 (+8 pad) bf16  (16.6 KB)
    __shared__ float wlds[16][64][HH];     // per-wave edge weights        (16 KB)
    __shared__ float mxl[16][HH];
    __shared__ float invl[16][HH];
    int wv = threadIdx.x >> 6;             // 0..15
    int lane = threadIdx.x & 63;
    int half = lane >> 5;                  // 0: edge j, 1: edge j+1
    int sl = lane & 31;                    // position within half-row
    int node16 = blockIdx.x * 16;
    int node = node16 + wv;                // NN % 16 == 0 -> always valid

    int s0 = start[node];
    int deg = start[node + 1] - s0;
    int sidx = (lane < deg) ? ssrc[s0 + lane] : 0;   // one coalesced load
    int soff = sidx << 8;                  // byte offset of this edge's h row

    const char* hb = (const char*)h;
    int lb8 = sl << 3;                     // byte offset within row: 8B per lane

    // paired-row address for load p covering edges jj (lanes<32) / jj+1 (lanes>=32)
    auto addrOf = [&](int jj) -> unsigned long long {
        int sa = __builtin_amdgcn_readlane(soff, jj);
        int sb = __builtin_amdgcn_readlane(soff, jj + 1);
        return (unsigned long long)(hb + ((half ? sb : sa) + lb8));
    };
    // issue 4 paired loads for the 8-edge chunk at j into named 64-bit regs
    auto issue4 = [&](int j, unsigned long long& h0, unsigned long long& h1,
                      unsigned long long& h2, unsigned long long& h3) {
        asm volatile("global_load_dwordx2 %0, %1, off" : "=v"(h0) : "v"(addrOf(j + 0)) : "memory");
        asm volatile("global_load_dwordx2 %0, %1, off" : "=v"(h1) : "v"(addrOf(j + 2)) : "memory");
        asm volatile("global_load_dwordx2 %0, %1, off" : "=v"(h2) : "v"(addrOf(j + 4)) : "memory");
        asm volatile("global_load_dwordx2 %0, %1, off" : "=v"(h3) : "v"(addrOf(j + 6)) : "memory");
    };

    int m = (deg > 64) ? 64 : deg;
    int nch = (m + 7) >> 3;                // >= 1 (deg >= 1 via self loop)
    unsigned long long pa0, pa1, pa2, pa3, pb0, pb1, pb2, pb3;
    issue4(0, pa0, pa1, pa2, pa3);         // chunk-0 issued before pass 1

    // ---- pass 1: softmax stats + LDS weights (wave-private; no barrier needed) ----
    {
        int jj = lane & 15;
        int hh = lane >> 4;
        float ad = a_d[node * HH + hh];
        float ec[4];
        float mx = -1e30f;
#pragma unroll
        for (int k = 0; k < 4; k++) {
            int j = jj + k * 16;
            float e = -1e30f;
            if (j < deg) {
                int s = __shfl(sidx, j);
                e = lrelu(a_s[s * HH + hh] + ad);
            }
            ec[k] = e;
            mx = fmaxf(mx, e);
        }
        for (int j = jj + 64; j < deg; j += 16) {   // rare fallback
            int s = ssrc[s0 + j];
            mx = fmaxf(mx, lrelu(a_s[s * HH + hh] + ad));
        }
#pragma unroll
        for (int off = 1; off < 16; off <<= 1) mx = fmaxf(mx, __shfl_xor(mx, off));
        float den = 0.f;
#pragma unroll
        for (int k = 0; k < 4; k++) {
            int j = jj + k * 16;
            float ww = __expf(ec[k] - mx);          // exactly 0 for pad slots
            den += ww;
            wlds[wv][j][hh] = ww;                   // all 64 slots written
        }
        for (int j = jj + 64; j < deg; j += 16) {   // rare fallback
            int s = ssrc[s0 + j];
            den += __expf(lrelu(a_s[s * HH + hh] + ad) - mx);
        }
#pragma unroll
        for (int off = 1; off < 16; off <<= 1) den += __shfl_xor(den, off);
        if (jj == 0) {
            invl[wv][hh] = 1.f / (den + EPSV);
            mxl[wv][hh] = mx;
        }
    }
    // NOTE: no __syncthreads() here — wlds/mxl/invl are only read by the same wave.

    // ---- pass 2: asm-pipelined paired-row aggregation ----
    f32x2 accA[HH];                        // dims sl*4, sl*4+1
    f32x2 accB[HH];                        // dims sl*4+2, sl*4+3
#pragma unroll
    for (int hh = 0; hh < HH; hh++) { accA[hh] = (f32x2){0.f, 0.f}; accB[hh] = (f32x2){0.f, 0.f}; }

    auto consume4 = [&](int j, unsigned long long h0, unsigned long long h1,
                        unsigned long long h2, unsigned long long h3) {
        unsigned xs[4] = {(unsigned)h0, (unsigned)h1, (unsigned)h2, (unsigned)h3};
        unsigned ys[4] = {(unsigned)(h0 >> 32), (unsigned)(h1 >> 32),
                          (unsigned)(h2 >> 32), (unsigned)(h3 >> 32)};
#pragma unroll
        for (int p = 0; p < 4; p++) {
            float4 w4 = *(const float4*)wlds[wv][j + 2 * p + half];  // this lane's edge
            f32x2 vA, vB;
            vA.x = __uint_as_float(xs[p] << 16);
            vA.y = __uint_as_float(xs[p] & 0xffff0000u);
            vB.x = __uint_as_float(ys[p] << 16);
            vB.y = __uint_as_float(ys[p] & 0xffff0000u);
            accA[0] += vA * w4.x; accB[0] += vB * w4.x;
            accA[1] += vA * w4.y; accB[1] += vB * w4.y;
            accA[2] += vA * w4.z; accB[2] += vB * w4.z;
            accA[3] += vA * w4.w; accB[3] += vB * w4.w;
        }
    };

#define WAIT4(H0, H1, H2, H3)                                                         \
    asm volatile("s_waitcnt vmcnt(4)" : "+v"(H0), "+v"(H1), "+v"(H2), "+v"(H3));      \
    __builtin_amdgcn_sched_barrier(0)
#define WAIT0(H0, H1, H2, H3)                                                         \
    asm volatile("s_waitcnt vmcnt(0)" : "+v"(H0), "+v"(H1), "+v"(H2), "+v"(H3));      \
    __builtin_amdgcn_sched_barrier(0)

    {
        int c = 0;
        for (;;) {                          // explicit ping-pong: static register names
            if (c + 1 < nch) {
                issue4((c + 1) * 8, pb0, pb1, pb2, pb3);
                WAIT4(pa0, pa1, pa2, pa3);
            } else {
                WAIT0(pa0, pa1, pa2, pa3);
            }
            consume4(c * 8, pa0, pa1, pa2, pa3);
            if (++c >= nch) break;
            if (c + 1 < nch) {
                issue4((c + 1) * 8, pa0, pa1, pa2, pa3);
                WAIT4(pb0, pb1, pb2, pb3);
            } else {
                WAIT0(pb0, pb1, pb2, pb3);
            }
            consume4(c * 8, pb0, pb1, pb2, pb3);
            if (++c >= nch) break;
        }
    }
#undef WAIT4
#undef WAIT0

    // rare fallback: deg > 64 -> recompute w inline; upper half weight=0 (no double count)
    for (int j = 64; j < deg; j++) {
        int s = ssrc[s0 + j];
        float4 as4 = *(const float4*)(a_s + (size_t)s * HH);
        float4 ad4 = *(const float4*)(a_d + (size_t)node * HH);
        float4 w4;
        float g = half ? 0.f : 1.f;
        w4.x = g * __expf(lrelu(as4.x + ad4.x) - mxl[wv][0]);
        w4.y = g * __expf(lrelu(as4.y + ad4.y) - mxl[wv][1]);
        w4.z = g * __expf(lrelu(as4.z + ad4.z) - mxl[wv][2]);
        w4.w = g * __expf(lrelu(as4.w + ad4.w) - mxl[wv][3]);
        uint2 hv = *(const uint2*)(hb + ((size_t)s << 8) + lb8);
        f32x2 vA, vB;
        vA.x = __uint_as_float(hv.x << 16);
        vA.y = __uint_as_float(hv.x & 0xffff0000u);
        vB.x = __uint_as_float(hv.y << 16);
        vB.y = __uint_as_float(hv.y & 0xffff0000u);
        accA[0] += vA * w4.x; accB[0] += vB * w4.x;
        accA[1] += vA * w4.y; accB[1] += vB * w4.y;
        accA[2] += vA * w4.z; accB[2] += vB * w4.z;
        accA[3] += vA * w4.w; accB[3] += vB * w4.w;
    }

    // cross-half reduce: both halves hold partial sums for the SAME dims
#pragma unroll
    for (int hh = 0; hh < HH; hh++) {
        accA[hh].x += __shfl_xor(accA[hh].x, 32);
        accA[hh].y += __shfl_xor(accA[hh].y, 32);
        accB[hh].x += __shfl_xor(accB[hh].x, 32);
        accB[hh].y += __shfl_xor(accB[hh].y, 32);
    }

    float4 inv4 = *(const float4*)invl[wv];
    float invs[HH] = {inv4.x, inv4.y, inv4.z, inv4.w};
    unsigned* aggU = (unsigned*)aggL;   // row stride PADS/2 = 260 uints
#pragma unroll
    for (int hh = 0; hh < HH; hh++) {
        f32x2 sel = half ? accB[hh] : accA[hh];   // uint index sl*2+half -> dims sl*4+2*half..+1
        unsigned packed = (unsigned)f2bu(sel.x * invs[hh]) |
                          ((unsigned)f2bu(sel.y * invs[hh]) << 16);
        aggU[wv * (PADS / 2) + hh * (DD / 2) + sl * 2 + half] = packed;
    }
    __syncthreads();

    // ---- phase 3: GEMM, waves 0..7 (one 16x16 col tile each) ----
    if (wv < 8) {
        int nt = wv;
        int r16 = lane & 15;
        int q = lane >> 4;
        const short* bb = (const short*)Bt;
        int brow = nt * 16 + r16;
        f32x4 gacc = {0.f, 0.f, 0.f, 0.f};
#pragma unroll
        for (int c = 0; c < 16; c++) {
            s16x8 a = *(const s16x8*)(aggL + r16 * PADS + c * 32 + q * 8);
            s16x8 b = *(const s16x8*)(bb + (size_t)brow * HD + c * 32 + q * 8);
            gacc = __builtin_amdgcn_mfma_f32_16x16x32_bf16(a, b, gacc, 0, 0, 0);
        }
        int cc = nt * 16 + r16;
        float bias = conv_b[cc];
#pragma unroll
        for (int r = 0; r < 4; r++) {
            int row = node16 + q * 4 + r;
            hnext[(size_t)row * DD + cc] = f2b(0.25f * gacc[r] + bias);
        }
    }
}

// ---------------- global mean pool accumulate (batch is sorted) ----------------
__global__ __launch_bounds__(256) void pool_accum2(const bf16* __restrict__ h,
                                                   const int* __restrict__ batch,
                                                   float* pooled) {
    int t = threadIdx.x;
    int d = t & 127;
    int half = t >> 7;
    int n0 = blockIdx.x * 64 + half * 32;
    int n1 = n0 + 32; if (n1 > NN) n1 = NN;
    float acc = 0.f;
    int cur = -1;
    for (int n = n0; n < n1; n++) {
        int g = batch[n];
        if ((unsigned)g >= GG) continue;
        if (g != cur) {
            if (cur >= 0) atomicAdd(&pooled[cur * DD + d], acc);
            acc = 0.f; cur = g;
        }
        acc += b2f(h[(size_t)n * DD + d]);
    }
    if (cur >= 0) atomicAdd(&pooled[cur * DD + d], acc);
}

// ---------------- FC1 MFMA (reads f32 pooled sums + counts directly) ----------------
__global__ __launch_bounds__(256) void fc1_mfma(const float* __restrict__ pooled,
                                                const int* __restrict__ counts,
                                                const bf16* __restrict__ gW1t,
                                                const float* __restrict__ gb1,
                                                bf16* __restrict__ t1) {
    int wid = (blockIdx.x * 256 + threadIdx.x) >> 6;  // 64*64 waves
    int lane = threadIdx.x & 63;
    int mt = wid >> 6;
    int nt = wid & 63;
    int r16 = lane & 15;
    int q = lane >> 4;
    int arow = mt * 16 + r16;
    int c0 = counts[arow]; if (c0 < 1) c0 = 1;
    float inv = 1.f / (float)c0;
    const short* bb = (const short*)gW1t;
    f32x4 acc = {0.f, 0.f, 0.f, 0.f};
    int brow = nt * 16 + r16;
#pragma unroll
    for (int c = 0; c < 4; c++) {
        const float* pr = pooled + (size_t)arow * DD + c * 32 + q * 8;
        float4 f0 = *(const float4*)pr;
        float4 f1 = *(const float4*)(pr + 4);
        s16x8 a;
        a[0] = (short)f2bu(f0.x * inv); a[1] = (short)f2bu(f0.y * inv);
        a[2] = (short)f2bu(f0.z * inv); a[3] = (short)f2bu(f0.w * inv);
        a[4] = (short)f2bu(f1.x * inv); a[5] = (short)f2bu(f1.y * inv);
        a[6] = (short)f2bu(f1.z * inv); a[7] = (short)f2bu(f1.w * inv);
        s16x8 b = *(const s16x8*)(bb + (size_t)brow * DD + c * 32 + q * 8);
        acc = __builtin_amdgcn_mfma_f32_16x16x32_bf16(a, b, acc, 0, 0, 0);
    }
    int cc = nt * 16 + r16;
    float bias = gb1[cc];
#pragma unroll
    for (int r = 0; r < 4; r++) {
        int row = mt * 16 + q * 4 + r;
        t1[(size_t)row * 1024 + cc] = f2b(fmaxf(acc[r] + bias, 0.f));
    }
}

// ---------------- FC2 MFMA ----------------
__global__ __launch_bounds__(256) void fc2_mfma(const bf16* __restrict__ t1,
                                                const bf16* __restrict__ gW2t,
                                                const float* __restrict__ gb2,
                                                float* __restrict__ out) {
    int wid = (blockIdx.x * 256 + threadIdx.x) >> 6;  // 64*8 waves
    int lane = threadIdx.x & 63;
    int mt = wid >> 3;
    int nt = wid & 7;
    int r16 = lane & 15;
    int q = lane >> 4;
    const short* ab = (const short*)t1;
    const short* bb = (const short*)gW2t;
    f32x4 acc = {0.f, 0.f, 0.f, 0.f};
    int arow = mt * 16 + r16;
    int brow = nt * 16 + r16;
#pragma unroll
    for (int c = 0; c < 32; c++) {
        s16x8 a = *(const s16x8*)(ab + (size_t)arow * 1024 + c * 32 + q * 8);
        s16x8 b = *(const s16x8*)(bb + (size_t)brow * 1024 + c * 32 + q * 8);
        acc = __builtin_amdgcn_mfma_f32_16x16x32_bf16(a, b, acc, 0, 0, 0);
    }
    int cc = nt * 16 + r16;
    float bias = gb2[cc];
#pragma unroll
    for (int r = 0; r < 4; r++) {
        int row = mt * 16 + q * 4 + r;
        out[(size_t)row * DD + cc] = acc[r] + bias;
    }
}

__global__ void sentinel_only(float* out, int hostcode) {
    if (threadIdx.x == 0 && blockIdx.x == 0) out[0] = (float)hostcode;
}

extern "C" void kernel_launch(void* const* d_in, const int* in_sizes, int n_in,
                              void* d_out, int out_size, void* d_ws, size_t ws_size,
                              hipStream_t stream) {
    float* out = (float*)d_out;

    static const int expect[15] = {3900000, 1600000, 50000, 9984, 128, 16384, 128,
                                   196608, 1536, 1536, 384, 131072, 1024, 131072, 128};
    int hostcode = 0;
    if (n_in != 15) hostcode = 21099;
    else for (int i = 0; i < 15; i++) if (in_sizes[i] != expect[i]) { hostcode = 21000 + i; break; }
    if (hostcode == 0 && out_size != GG * DD) hostcode = 35000;

    const float* x       = (const float*)d_in[0];
    const float* W1      = (const float*)d_in[3];
    const float* b1      = (const float*)d_in[4];
    const float* W2      = (const float*)d_in[5];
    const float* b2      = (const float*)d_in[6];
    const float* lin_w   = (const float*)d_in[7];
    const float* att_src = (const float*)d_in[8];
    const float* att_dst = (const float*)d_in[9];
    const float* conv_b  = (const float*)d_in[10];
    const float* gW1     = (const float*)d_in[11];
    const float* gb1     = (const float*)d_in[12];
    const float* gW2     = (const float*)d_in[13];
    const float* gb2     = (const float*)d_in[14];

    char* p = (char*)d_ws;
    auto alloc = [&](size_t bytes) { void* q = (void*)p; p += (bytes + 255) & ~(size_t)255; return q; };
    int*   ei32   = (int*)alloc((size_t)2 * EE * 4);
    int*   bat32  = (int*)alloc((size_t)NN * 4);
    bf16*  xb     = (bf16*)alloc((size_t)NN * K1P * 2);
    bf16*  W1tb   = (bf16*)alloc((size_t)DD * K1P * 2);
    bf16*  W2tb   = (bf16*)alloc((size_t)DD * DD * 2);
    bf16*  hA     = (bf16*)alloc((size_t)NN * DD * 2);
    bf16*  hB     = (bf16*)alloc((size_t)NN * DD * 2);
    bf16*  Bt     = (bf16*)alloc((size_t)LL * DD * HD * 2);
    float* wsbuf  = (float*)alloc((size_t)LL * DD * HH * 4);
    float* wdbuf  = (float*)alloc((size_t)LL * DD * HH * 4);
    float* a_sA   = (float*)alloc((size_t)NN * HH * 4);
    float* a_dA   = (float*)alloc((size_t)NN * HH * 4);
    int*   deg    = (int*)alloc((size_t)NN * 4);
    int*   start  = (int*)alloc((size_t)(NN + 1) * 4);
    int*   cursor = (int*)alloc((size_t)NN * 4);
    int*   ssrc   = (int*)alloc((size_t)ET * 4);
    int*   bsum   = (int*)alloc((size_t)SB * 4);
    int*   boff   = (int*)alloc((size_t)SB * 4);
    float* pooled = (float*)alloc((size_t)GG * DD * 4);
    int*   counts = (int*)alloc((size_t)GG * 4);
    bf16*  gW1t   = (bf16*)alloc((size_t)1024 * DD * 2);
    bf16*  gW2t   = (bf16*)alloc((size_t)DD * 1024 * 2);
    bf16*  t1buf  = (bf16*)alloc((size_t)GG * 1024 * 2);
    size_t need = (size_t)(p - (char*)d_ws);
    if (hostcode == 0 && ws_size < need) hostcode = 34000;

    if (hostcode != 0) {
        sentinel_only<<<1, 64, 0, stream>>>(out, hostcode);
        return;
    }

    // prep FIRST: zeroes counts/pooled (before conv_batch atomics) and deg (before conv_edges atomics)
    prep_misc<<<(PRE6 + 255) / 256, 256, 0, stream>>>(x, W1, W2, lin_w, att_src, att_dst, gW1, gW2,
                                                      xb, W1tb, W2tb, Bt, wsbuf, wdbuf, gW1t, gW2t,
                                                      pooled, counts, deg);
    conv_edges<<<(2 * EE + 255) / 256, 256, 0, stream>>>(d_in[1], ei32, deg);
    conv_batch<<<(NN + 255) / 256, 256, 0, stream>>>(d_in[2], bat32, counts);

    mlp_fused<<<(NN / 16 * 64 + 255) / 256, 256, 0, stream>>>(xb, W1tb, b1, W2tb, b2,
                                                              wsbuf, wdbuf, hA, a_sA, a_dA);

    block_sums<<<SB, 256, 0, stream>>>(deg, bsum);
    scan_bsum<<<1, 256, 0, stream>>>(bsum, boff, start);
    scan_final<<<SB, 256, 0, stream>>>(deg, boff, start, cursor);
    scatter_all<<<(NN + EE + 255) / 256, 256, 0, stream>>>(ei32, cursor, ssrc);

    bf16* hin = hA;
    bf16* hout = hB;
    for (int l = 0; l < LL; l++) {
        if (l > 0)   // layer 0's a_s/a_d comes fused from mlp_fused
            a_sd2<<<(NN + 255) / 256, 256, 0, stream>>>(hin, wsbuf + (size_t)l * DD * HH,
                                                        wdbuf + (size_t)l * DD * HH, a_sA, a_dA);
        agg_gemm<<<NN / 16, 1024, 0, stream>>>(start, ssrc, a_sA, a_dA, hin,
                                               Bt + (size_t)l * DD * HD, conv_b + l * DD, hout);
        bf16* tmp = hin; hin = hout; hout = tmp;
    }
    pool_accum2<<<(NN + 63) / 64, 256, 0, stream>>>(hin, bat32, pooled);
    fc1_mfma<<<(64 * 64) / 4, 256, 0, stream>>>(pooled, counts, gW1t, gb1, t1buf);
    fc2_mfma<<<(64 * 8) / 4, 256, 0, stream>>>(t1buf, gW2t, gb2, out);
}

// Round 19
// 552.411 us; speedup vs baseline: 1.0137x; 1.0137x over previous
//
#include <hip/hip_runtime.h>
#include <hip/hip_bf16.h>

#define NN 50000   // nodes
#define EE 800000  // directed edges (no self loops)
#define ET 850000  // EE + NN self loops
#define GG 1024    // graphs
#define DD 128     // embedding dim
#define HH 4       // heads
#define LL 3       // layers
#define ND 78      // node feature dim
#define HD 512     // HH*DD
#define K1P 96     // node-dim padded to multiple of 32 for MFMA
#define SLOPE 0.2f
#define EPSV 1e-16f
#define SB 196     // scan blocks = ceil(NN/256)
#define PADS 520   // LDS row stride in shorts (512 + 8 pad)

typedef __hip_bfloat16 bf16;
typedef __attribute__((ext_vector_type(8))) unsigned short u16x8;
typedef __attribute__((ext_vector_type(8))) short s16x8;   // MFMA A/B fragment (8 bf16)
typedef __attribute__((ext_vector_type(4))) float f32x4;   // MFMA C/D fragment
typedef __attribute__((ext_vector_type(2))) float f32x2;   // packed fp32 (v_pk_fma_f32)

__device__ __forceinline__ float b2f(bf16 v) { return __bfloat162float(v); }
__device__ __forceinline__ bf16 f2b(float v) { return __float2bfloat16(v); }
__device__ __forceinline__ float bu2f(unsigned short u) {
    return __uint_as_float(((unsigned)u) << 16);
}
__device__ __forceinline__ unsigned short f2bu(float f) {
    unsigned u = __float_as_uint(f);
    unsigned rounded = u + 0x7FFFu + ((u >> 16) & 1u);
    return (unsigned short)(rounded >> 16);
}
__device__ __forceinline__ float lrelu(float e) { return (e > 0.f) ? e : SLOPE * e; }

// ---------------- fused preprocessing (region-dispatched; xb/PRE0 removed) ----------------
// R0 nw_conv | R1 wt2_conv | R2 gw_conv | R3 asd_w | R4 pool_init | R5 deg_init
#define PRE0 (DD * K1P + DD * DD)          // 28,672
#define PRE1 (PRE0 + LL * DD * HD)         // + 196,608 -> 225,280
#define PRE2 (PRE1 + 2 * 1024 * DD)        // + 262,144 -> 487,424
#define PRE3 (PRE2 + LL * DD * HH)         // + 1,536   -> 488,960
#define PRE4 (PRE3 + GG * DD + GG)         // + 132,096 -> 621,056
#define PRE5 (PRE4 + NN)                   // + 50,000  -> 671,056
__global__ void prep_misc(const float* __restrict__ W1, const float* __restrict__ W2,
                          const float* __restrict__ lin_w,
                          const float* __restrict__ att_src, const float* __restrict__ att_dst,
                          const float* __restrict__ gW1, const float* __restrict__ gW2,
                          bf16* __restrict__ W1t, bf16* __restrict__ W2t,
                          bf16* __restrict__ Bt, float* __restrict__ ws, float* __restrict__ wd,
                          bf16* __restrict__ gW1t, bf16* __restrict__ gW2t,
                          float* __restrict__ pooled, int* __restrict__ counts,
                          int* __restrict__ deg) {
    int idx = blockIdx.x * 256 + threadIdx.x;
    if (idx < PRE0) {                       // nw_conv
        if (idx < DD * K1P) {
            int c = idx / K1P, k = idx % K1P;
            W1t[idx] = f2b((k < ND) ? W1[(size_t)k * DD + c] : 0.f);
        } else {
            idx -= DD * K1P;
            int c = idx / DD, k = idx % DD;
            W2t[idx] = f2b(W2[(size_t)k * DD + c]);
        }
        return;
    }
    if (idx < PRE1) {                       // wt2_conv: Bt[l][c][k=h*128+d]
        idx -= PRE0;
        int l = idx / (DD * HD);
        int rem = idx % (DD * HD);
        int c = rem / HD;
        int k = rem % HD;
        int h = k >> 7;
        int d = k & 127;
        Bt[idx] = f2b(lin_w[((size_t)(l * DD + d) * HH + h) * DD + c]);
        return;
    }
    if (idx < PRE2) {                       // gw_conv
        idx -= PRE1;
        if (idx < 1024 * DD) {
            int c = idx / DD, k = idx % DD;
            gW1t[idx] = f2b(gW1[(size_t)k * 1024 + c]);
        } else {
            idx -= 1024 * DD;
            int c = idx / 1024, k = idx % 1024;
            gW2t[idx] = f2b(gW2[(size_t)k * DD + c]);
        }
        return;
    }
    if (idx < PRE3) {                       // asd_w: ws/wd [L][D][H]
        idx -= PRE2;
        int l = idx / (DD * HH);
        int rem = idx % (DD * HH);
        int d = rem >> 2;
        int h = rem & 3;
        const float* wrow = lin_w + ((size_t)(l * DD + d) * HH + h) * DD;
        const float* as = att_src + (size_t)(l * HH + h) * DD;
        const float* ad = att_dst + (size_t)(l * HH + h) * DD;
        float s1 = 0.f, s2 = 0.f;
        for (int e = 0; e < DD; e++) { float w = wrow[e]; s1 += w * as[e]; s2 += w * ad[e]; }
        ws[idx] = s1;
        wd[idx] = s2;
        return;
    }
    if (idx < PRE4) {                       // pool_init (counts/pooled zero BEFORE conv atomics)
        idx -= PRE3;
        if (idx < GG * DD) pooled[idx] = 0.f;
        if (idx < GG) counts[idx] = 0;
        return;
    }
    if (idx < PRE5) {                       // deg init (self loop = 1) BEFORE conv atomics
        deg[idx - PRE4] = 1;
    }
}

// ---------------- edges + batch conversion in ONE kernel (region-dispatched) ----------------
// Blocks [0, 2EE/256): edge conversion + dst histogram.  2EE = 1,600,000 = 6250*256,
// so the region boundary is block-aligned -> no divergent barriers.
// Blocks after: batch conversion + per-graph counts. Per-block inline int-width detect
// samples the block's own source buffer.
__global__ void conv_all(const void* __restrict__ esrc, const void* __restrict__ bsrc,
                         int* __restrict__ ei, int* __restrict__ bat,
                         int* __restrict__ deg, int* __restrict__ counts) {
    __shared__ int z;
    int t = threadIdx.x;
    int i = blockIdx.x * 256 + t;
    if (i < 2 * EE) {                       // edge region
        const unsigned* w = (const unsigned*)esrc;
        if (t == 0) z = 0;
        __syncthreads();
        if (w[2 * t + 1] == 0u) atomicAdd(&z, 1);
        __syncthreads();
        int flag = (z >= 200) ? 1 : 0;
        const int* s = (const int*)esrc;
        int g = flag ? s[2 * i] : s[i];
        ei[i] = g;
        if (i >= EE && (unsigned)g < NN) atomicAdd(&deg[g], 1);
    } else {                                // batch region
        int i2 = i - 2 * EE;
        const unsigned* w = (const unsigned*)bsrc;
        if (t == 0) z = 0;
        __syncthreads();
        if (w[2 * t + 1] == 0u) atomicAdd(&z, 1);
        __syncthreads();
        int flag = (z >= 200) ? 1 : 0;
        if (i2 >= NN) return;
        const int* s = (const int*)bsrc;
        int g = flag ? s[2 * i2] : s[i2];
        bat[i2] = g;
        if ((unsigned)g < GG) atomicAdd(&counts[g], 1);
    }
}

// ---------------- FUSED node MLP: reads x DIRECTLY (xb buffer eliminated) ----------------
__global__ __launch_bounds__(256) void mlp_fused(const float* __restrict__ x,
                                                 const bf16* __restrict__ W1t,
                                                 const float* __restrict__ b1,
                                                 const bf16* __restrict__ W2t,
                                                 const float* __restrict__ b2,
                                                 const float* __restrict__ ws0,
                                                 const float* __restrict__ wd0,
                                                 bf16* __restrict__ h,
                                                 float* __restrict__ a_s, float* __restrict__ a_d) {
    __shared__ __align__(16) short tsl[4][16][136];   // per-wave ts tile; 136-short stride
    int wv4 = threadIdx.x >> 6;
    int wid = (blockIdx.x * 256 + threadIdx.x) >> 6;
    if (wid >= NN / 16) return;            // no barriers in kernel -> early exit safe
    int lane = threadIdx.x & 63;
    int r16 = lane & 15;
    int q = lane >> 4;

    // ---- phase A: ts = relu(x @ W1^T + b1) -> LDS (A-frag built from f32 x, zero-pad k>=78) ----
    {
        const short* bb = (const short*)W1t;
        int arow = wid * 16 + r16;
        const float* xr = x + (size_t)arow * ND;
        s16x8 afr[3];
#pragma unroll
        for (int c = 0; c < 3; c++) {
#pragma unroll
            for (int j = 0; j < 8; j++) {
                int k = c * 32 + q * 8 + j;
                float v = (k < ND) ? xr[k] : 0.f;
                afr[c][j] = (short)f2bu(v);
            }
        }
#pragma unroll
        for (int nt = 0; nt < 8; nt++) {
            int brow = nt * 16 + r16;
            f32x4 acc = {0.f, 0.f, 0.f, 0.f};
#pragma unroll
            for (int c = 0; c < 3; c++) {
                s16x8 b = *(const s16x8*)(bb + (size_t)brow * K1P + c * 32 + q * 8);
                acc = __builtin_amdgcn_mfma_f32_16x16x32_bf16(afr[c], b, acc, 0, 0, 0);
            }
            int cc = nt * 16 + r16;
            float bias = b1[cc];
#pragma unroll
            for (int r = 0; r < 4; r++)
                tsl[wv4][q * 4 + r][cc] = (short)f2bu(fmaxf(acc[r] + bias, 0.f));
        }
    }

    // ---- phase B: h = ts @ W2t^T + b2 (A from LDS), + layer-0 a_s/a_d partials ----
    {
        const short* bb = (const short*)W2t;
        s16x8 afr[4];
#pragma unroll
        for (int c = 0; c < 4; c++)
            afr[c] = *(const s16x8*)(&tsl[wv4][r16][c * 32 + q * 8]);
        float part[4][8];
#pragma unroll
        for (int r = 0; r < 4; r++)
#pragma unroll
            for (int k = 0; k < 8; k++) part[r][k] = 0.f;
#pragma unroll
        for (int nt = 0; nt < 8; nt++) {
            int brow = nt * 16 + r16;
            f32x4 acc = {0.f, 0.f, 0.f, 0.f};
#pragma unroll
            for (int c = 0; c < 4; c++) {
                s16x8 b = *(const s16x8*)(bb + (size_t)brow * DD + c * 32 + q * 8);
                acc = __builtin_amdgcn_mfma_f32_16x16x32_bf16(afr[c], b, acc, 0, 0, 0);
            }
            int cc = nt * 16 + r16;
            float bias = b2[cc];
            float4 w4s = *(const float4*)(ws0 + cc * 4);
            float4 w4d = *(const float4*)(wd0 + cc * 4);
#pragma unroll
            for (int r = 0; r < 4; r++) {
                unsigned short us = f2bu(acc[r] + bias);
                int row = wid * 16 + q * 4 + r;
                ((unsigned short*)h)[(size_t)row * DD + cc] = us;
                float v = bu2f(us);   // use ROUNDED value (matches a_sd2-from-bf16 path)
                part[r][0] += v * w4s.x; part[r][1] += v * w4s.y;
                part[r][2] += v * w4s.z; part[r][3] += v * w4s.w;
                part[r][4] += v * w4d.x; part[r][5] += v * w4d.y;
                part[r][6] += v * w4d.z; part[r][7] += v * w4d.w;
            }
        }
#pragma unroll
        for (int r = 0; r < 4; r++)
#pragma unroll
            for (int k = 0; k < 8; k++) {
                float v = part[r][k];
                v += __shfl_xor(v, 1); v += __shfl_xor(v, 2);
                v += __shfl_xor(v, 4); v += __shfl_xor(v, 8);
                part[r][k] = v;
            }
        if (r16 == 0) {
#pragma unroll
            for (int r = 0; r < 4; r++) {
                int row = wid * 16 + q * 4 + r;
                *(float4*)(a_s + (size_t)row * 4) =
                    make_float4(part[r][0], part[r][1], part[r][2], part[r][3]);
                *(float4*)(a_d + (size_t)row * 4) =
                    make_float4(part[r][4], part[r][5], part[r][6], part[r][7]);
            }
        }
    }
}

// ---------------- a_s,a_d from h (layers 1,2): one thread per node ----------------
__global__ __launch_bounds__(256) void a_sd2(const bf16* __restrict__ h,
                                             const float* __restrict__ ws,
                                             const float* __restrict__ wd,
                                             float* __restrict__ a_s, float* __restrict__ a_d) {
    __shared__ float wsl[DD][HH];
    __shared__ float wdl[DD][HH];
    int t = threadIdx.x;
    for (int i = t; i < DD * HH; i += 256) { wsl[i >> 2][i & 3] = ws[i]; wdl[i >> 2][i & 3] = wd[i]; }
    __syncthreads();
    int n = blockIdx.x * 256 + t;
    if (n >= NN) return;
    const u16x8* row = (const u16x8*)((const unsigned short*)h + (size_t)n * DD);
    float s1[HH] = {0.f, 0.f, 0.f, 0.f};
    float s2[HH] = {0.f, 0.f, 0.f, 0.f};
    for (int c = 0; c < 16; c++) {
        u16x8 v = row[c];
#pragma unroll
        for (int k = 0; k < 8; k++) {
            int d = c * 8 + k;
            float f = bu2f(v[k]);
#pragma unroll
            for (int hh = 0; hh < HH; hh++) {
                s1[hh] += f * wsl[d][hh];
                s2[hh] += f * wdl[d][hh];
            }
        }
    }
#pragma unroll
    for (int hh = 0; hh < HH; hh++) {
        a_s[n * HH + hh] = s1[hh];
        a_d[n * HH + hh] = s2[hh];
    }
}

// ---------------- counting sort scan (scan_bsum folded into scan_final) ----------------
__global__ __launch_bounds__(256) void block_sums(const int* __restrict__ deg, int* __restrict__ bsum) {
    __shared__ int part[256];
    int t = threadIdx.x;
    int i = blockIdx.x * 256 + t;
    part[t] = (i < NN) ? deg[i] : 0;
    __syncthreads();
    for (int off = 128; off > 0; off >>= 1) {
        if (t < off) part[t] += part[t + off];
        __syncthreads();
    }
    if (t == 0) bsum[blockIdx.x] = part[0];
}
// every block redundantly scans bsum[196] in LDS (cheap), then does its own 256-elem scan
__global__ __launch_bounds__(256) void scan_final2(const int* __restrict__ deg,
                                                   const int* __restrict__ bsum,
                                                   int* __restrict__ start, int* __restrict__ cursor) {
    __shared__ int bpart[256];
    __shared__ int part[256];
    int t = threadIdx.x;
    bpart[t] = (t < SB) ? bsum[t] : 0;
    __syncthreads();
    for (int off = 1; off < 256; off <<= 1) {
        int add = (t >= off) ? bpart[t - off] : 0;
        __syncthreads();
        bpart[t] += add;
        __syncthreads();
    }
    int i = blockIdx.x * 256 + t;
    int v = (i < NN) ? deg[i] : 0;
    part[t] = v;
    __syncthreads();
    for (int off = 1; off < 256; off <<= 1) {
        int add = (t >= off) ? part[t - off] : 0;
        __syncthreads();
        part[t] += add;
        __syncthreads();
    }
    if (i < NN) {
        int boffv = (blockIdx.x == 0) ? 0 : bpart[blockIdx.x - 1];
        int ex = boffv + part[t] - v;
        start[i] = ex;
        cursor[i] = ex;
    }
    if (blockIdx.x == 0 && t == 0) start[NN] = bpart[SB - 1];
}
__global__ void scatter_all(const int* __restrict__ ei, int* cursor, int* ssrc) {
    int i = blockIdx.x * 256 + threadIdx.x;
    if (i < NN) {
        int pos = atomicAdd(&cursor[i], 1);
        if ((unsigned)pos < ET) ssrc[pos] = i;
        return;
    }
    int e = i - NN;
    if (e >= EE) return;
    int src = ei[e];
    int dst = ei[EE + e];
    if ((unsigned)dst >= NN) return;
    int pos = atomicAdd(&cursor[dst], 1);
    if ((unsigned)pos < ET) ssrc[pos] = ((unsigned)src < NN) ? src : 0;
}

// ---------------- FUSED: edge softmax + aggregate 16 nodes + post-GEMM (MFMA) ----------------
// Pass-2 structure DECLARED PINNED at ~95us: four independent concurrency manipulations
// (R3 bursty-8, R6 paired-4, R8 source ping-pong, R13 asm-forced 8-deep counted-vmcnt)
// all land 94.5-99us. ~218MB/dispatch logical random 256B-row gather through the
// L2-miss path at ~1.2-1.45 TB/s effective = the measured time; CU memory queues are
// saturated by ~32 waves/CU already. Keeping the asm variant (marginally fastest).
__global__ __launch_bounds__(1024, 8) void agg_gemm(const int* __restrict__ start,
                                                    const int* __restrict__ ssrc,
                                                    const float* __restrict__ a_s,
                                                    const float* __restrict__ a_d,
                                                    const bf16* __restrict__ h,
                                                    const bf16* __restrict__ Bt,
                                                    const float* __restrict__ conv_b,
                                                    bf16* __restrict__ hnext) {
    __shared__ short aggL[16 * PADS];      // 16 rows x 512 (+8 pad) bf16  (16.6 KB)
    __shared__ float wlds[16][64][HH];     // per-wave edge weights        (16 KB)
    __shared__ float mxl[16][HH];
    __shared__ float invl[16][HH];
    int wv = threadIdx.x >> 6;             // 0..15
    int lane = threadIdx.x & 63;
    int half = lane >> 5;                  // 0: edge j, 1: edge j+1
    int sl = lane & 31;                    // position within half-row
    int node16 = blockIdx.x * 16;
    int node = node16 + wv;                // NN % 16 == 0 -> always valid

    int s0 = start[node];
    int deg = start[node + 1] - s0;
    int sidx = (lane < deg) ? ssrc[s0 + lane] : 0;   // one coalesced load
    int soff = sidx << 8;                  // byte offset of this edge's h row

    const char* hb = (const char*)h;
    int lb8 = sl << 3;                     // byte offset within row: 8B per lane

    auto addrOf = [&](int jj) -> unsigned long long {
        int sa = __builtin_amdgcn_readlane(soff, jj);
        int sb = __builtin_amdgcn_readlane(soff, jj + 1);
        return (unsigned long long)(hb + ((half ? sb : sa) + lb8));
    };
    auto issue4 = [&](int j, unsigned long long& h0, unsigned long long& h1,
                      unsigned long long& h2, unsigned long long& h3) {
        asm volatile("global_load_dwordx2 %0, %1, off" : "=v"(h0) : "v"(addrOf(j + 0)) : "memory");
        asm volatile("global_load_dwordx2 %0, %1, off" : "=v"(h1) : "v"(addrOf(j + 2)) : "memory");
        asm volatile("global_load_dwordx2 %0, %1, off" : "=v"(h2) : "v"(addrOf(j + 4)) : "memory");
        asm volatile("global_load_dwordx2 %0, %1, off" : "=v"(h3) : "v"(addrOf(j + 6)) : "memory");
    };

    int m = (deg > 64) ? 64 : deg;
    int nch = (m + 7) >> 3;                // >= 1 (deg >= 1 via self loop)
    unsigned long long pa0, pa1, pa2, pa3, pb0, pb1, pb2, pb3;
    issue4(0, pa0, pa1, pa2, pa3);         // chunk-0 issued before pass 1

    // ---- pass 1: softmax stats + LDS weights (wave-private; no barrier needed) ----
    {
        int jj = lane & 15;
        int hh = lane >> 4;
        float ad = a_d[node * HH + hh];
        float ec[4];
        float mx = -1e30f;
#pragma unroll
        for (int k = 0; k < 4; k++) {
            int j = jj + k * 16;
            float e = -1e30f;
            if (j < deg) {
                int s = __shfl(sidx, j);
                e = lrelu(a_s[s * HH + hh] + ad);
            }
            ec[k] = e;
            mx = fmaxf(mx, e);
        }
        for (int j = jj + 64; j < deg; j += 16) {   // rare fallback
            int s = ssrc[s0 + j];
            mx = fmaxf(mx, lrelu(a_s[s * HH + hh] + ad));
        }
#pragma unroll
        for (int off = 1; off < 16; off <<= 1) mx = fmaxf(mx, __shfl_xor(mx, off));
        float den = 0.f;
#pragma unroll
        for (int k = 0; k < 4; k++) {
            int j = jj + k * 16;
            float ww = __expf(ec[k] - mx);          // exactly 0 for pad slots
            den += ww;
            wlds[wv][j][hh] = ww;                   // all 64 slots written
        }
        for (int j = jj + 64; j < deg; j += 16) {   // rare fallback
            int s = ssrc[s0 + j];
            den += __expf(lrelu(a_s[s * HH + hh] + ad) - mx);
        }
#pragma unroll
        for (int off = 1; off < 16; off <<= 1) den += __shfl_xor(den, off);
        if (jj == 0) {
            invl[wv][hh] = 1.f / (den + EPSV);
            mxl[wv][hh] = mx;
        }
    }
    // NOTE: no __syncthreads() here — wlds/mxl/invl are only read by the same wave.

    // ---- pass 2: asm-pipelined paired-row aggregation ----
    f32x2 accA[HH];                        // dims sl*4, sl*4+1
    f32x2 accB[HH];                        // dims sl*4+2, sl*4+3
#pragma unroll
    for (int hh = 0; hh < HH; hh++) { accA[hh] = (f32x2){0.f, 0.f}; accB[hh] = (f32x2){0.f, 0.f}; }

    auto consume4 = [&](int j, unsigned long long h0, unsigned long long h1,
                        unsigned long long h2, unsigned long long h3) {
        unsigned xs[4] = {(unsigned)h0, (unsigned)h1, (unsigned)h2, (unsigned)h3};
        unsigned ys[4] = {(unsigned)(h0 >> 32), (unsigned)(h1 >> 32),
                          (unsigned)(h2 >> 32), (unsigned)(h3 >> 32)};
#pragma unroll
        for (int p = 0; p < 4; p++) {
            float4 w4 = *(const float4*)wlds[wv][j + 2 * p + half];  // this lane's edge
            f32x2 vA, vB;
            vA.x = __uint_as_float(xs[p] << 16);
            vA.y = __uint_as_float(xs[p] & 0xffff0000u);
            vB.x = __uint_as_float(ys[p] << 16);
            vB.y = __uint_as_float(ys[p] & 0xffff0000u);
            accA[0] += vA * w4.x; accB[0] += vB * w4.x;
            accA[1] += vA * w4.y; accB[1] += vB * w4.y;
            accA[2] += vA * w4.z; accB[2] += vB * w4.z;
            accA[3] += vA * w4.w; accB[3] += vB * w4.w;
        }
    };

#define WAIT4(H0, H1, H2, H3)                                                         \
    asm volatile("s_waitcnt vmcnt(4)" : "+v"(H0), "+v"(H1), "+v"(H2), "+v"(H3));      \
    __builtin_amdgcn_sched_barrier(0)
#define WAIT0(H0, H1, H2, H3)                                                         \
    asm volatile("s_waitcnt vmcnt(0)" : "+v"(H0), "+v"(H1), "+v"(H2), "+v"(H3));      \
    __builtin_amdgcn_sched_barrier(0)

    {
        int c = 0;
        for (;;) {                          // explicit ping-pong: static register names
            if (c + 1 < nch) {
                issue4((c + 1) * 8, pb0, pb1, pb2, pb3);
                WAIT4(pa0, pa1, pa2, pa3);
            } else {
                WAIT0(pa0, pa1, pa2, pa3);
            }
            consume4(c * 8, pa0, pa1, pa2, pa3);
            if (++c >= nch) break;
            if (c + 1 < nch) {
                issue4((c + 1) * 8, pa0, pa1, pa2, pa3);
                WAIT4(pb0, pb1, pb2, pb3);
            } else {
                WAIT0(pb0, pb1, pb2, pb3);
            }
            consume4(c * 8, pb0, pb1, pb2, pb3);
            if (++c >= nch) break;
        }
    }
#undef WAIT4
#undef WAIT0

    // rare fallback: deg > 64 -> recompute w inline; upper half weight=0 (no double count)
    for (int j = 64; j < deg; j++) {
        int s = ssrc[s0 + j];
        float4 as4 = *(const float4*)(a_s + (size_t)s * HH);
        float4 ad4 = *(const float4*)(a_d + (size_t)node * HH);
        float4 w4;
        float g = half ? 0.f : 1.f;
        w4.x = g * __expf(lrelu(as4.x + ad4.x) - mxl[wv][0]);
        w4.y = g * __expf(lrelu(as4.y + ad4.y) - mxl[wv][1]);
        w4.z = g * __expf(lrelu(as4.z + ad4.z) - mxl[wv][2]);
        w4.w = g * __expf(lrelu(as4.w + ad4.w) - mxl[wv][3]);
        uint2 hv = *(const uint2*)(hb + ((size_t)s << 8) + lb8);
        f32x2 vA, vB;
        vA.x = __uint_as_float(hv.x << 16);
        vA.y = __uint_as_float(hv.x & 0xffff0000u);
        vB.x = __uint_as_float(hv.y << 16);
        vB.y = __uint_as_float(hv.y & 0xffff0000u);
        accA[0] += vA * w4.x; accB[0] += vB * w4.x;
        accA[1] += vA * w4.y; accB[1] += vB * w4.y;
        accA[2] += vA * w4.z; accB[2] += vB * w4.z;
        accA[3] += vA * w4.w; accB[3] += vB * w4.w;
    }

    // cross-half reduce: both halves hold partial sums for the SAME dims
#pragma unroll
    for (int hh = 0; hh < HH; hh++) {
        accA[hh].x += __shfl_xor(accA[hh].x, 32);
        accA[hh].y += __shfl_xor(accA[hh].y, 32);
        accB[hh].x += __shfl_xor(accB[hh].x, 32);
        accB[hh].y += __shfl_xor(accB[hh].y, 32);
    }

    float4 inv4 = *(const float4*)invl[wv];
    float invs[HH] = {inv4.x, inv4.y, inv4.z, inv4.w};
    unsigned* aggU = (unsigned*)aggL;   // row stride PADS/2 = 260 uints
#pragma unroll
    for (int hh = 0; hh < HH; hh++) {
        f32x2 sel = half ? accB[hh] : accA[hh];   // uint index sl*2+half -> dims sl*4+2*half..+1
        unsigned packed = (unsigned)f2bu(sel.x * invs[hh]) |
                          ((unsigned)f2bu(sel.y * invs[hh]) << 16);
        aggU[wv * (PADS / 2) + hh * (DD / 2) + sl * 2 + half] = packed;
    }
    __syncthreads();

    // ---- phase 3: GEMM, waves 0..7 (one 16x16 col tile each) ----
    if (wv < 8) {
        int nt = wv;
        int r16 = lane & 15;
        int q = lane >> 4;
        const short* bb = (const short*)Bt;
        int brow = nt * 16 + r16;
        f32x4 gacc = {0.f, 0.f, 0.f, 0.f};
#pragma unroll
        for (int c = 0; c < 16; c++) {
            s16x8 a = *(const s16x8*)(aggL + r16 * PADS + c * 32 + q * 8);
            s16x8 b = *(const s16x8*)(bb + (size_t)brow * HD + c * 32 + q * 8);
            gacc = __builtin_amdgcn_mfma_f32_16x16x32_bf16(a, b, gacc, 0, 0, 0);
        }
        int cc = nt * 16 + r16;
        float bias = conv_b[cc];
#pragma unroll
        for (int r = 0; r < 4; r++) {
            int row = node16 + q * 4 + r;
            hnext[(size_t)row * DD + cc] = f2b(0.25f * gacc[r] + bias);
        }
    }
}

// ---------------- global mean pool accumulate (batch is sorted) ----------------
__global__ __launch_bounds__(256) void pool_accum2(const bf16* __restrict__ h,
                                                   const int* __restrict__ batch,
                                                   float* pooled) {
    int t = threadIdx.x;
    int d = t & 127;
    int half = t >> 7;
    int n0 = blockIdx.x * 64 + half * 32;
    int n1 = n0 + 32; if (n1 > NN) n1 = NN;
    float acc = 0.f;
    int cur = -1;
    for (int n = n0; n < n1; n++) {
        int g = batch[n];
        if ((unsigned)g >= GG) continue;
        if (g != cur) {
            if (cur >= 0) atomicAdd(&pooled[cur * DD + d], acc);
            acc = 0.f; cur = g;
        }
        acc += b2f(h[(size_t)n * DD + d]);
    }
    if (cur >= 0) atomicAdd(&pooled[cur * DD + d], acc);
}

// ---------------- FC1 MFMA (reads f32 pooled sums + counts directly) ----------------
__global__ __launch_bounds__(256) void fc1_mfma(const float* __restrict__ pooled,
                                                const int* __restrict__ counts,
                                                const bf16* __restrict__ gW1t,
                                                const float* __restrict__ gb1,
                                                bf16* __restrict__ t1) {
    int wid = (blockIdx.x * 256 + threadIdx.x) >> 6;  // 64*64 waves
    int lane = threadIdx.x & 63;
    int mt = wid >> 6;
    int nt = wid & 63;
    int r16 = lane & 15;
    int q = lane >> 4;
    int arow = mt * 16 + r16;
    int c0 = counts[arow]; if (c0 < 1) c0 = 1;
    float inv = 1.f / (float)c0;
    const short* bb = (const short*)gW1t;
    f32x4 acc = {0.f, 0.f, 0.f, 0.f};
    int brow = nt * 16 + r16;
#pragma unroll
    for (int c = 0; c < 4; c++) {
        const float* pr = pooled + (size_t)arow * DD + c * 32 + q * 8;
        float4 f0 = *(const float4*)pr;
        float4 f1 = *(const float4*)(pr + 4);
        s16x8 a;
        a[0] = (short)f2bu(f0.x * inv); a[1] = (short)f2bu(f0.y * inv);
        a[2] = (short)f2bu(f0.z * inv); a[3] = (short)f2bu(f0.w * inv);
        a[4] = (short)f2bu(f1.x * inv); a[5] = (short)f2bu(f1.y * inv);
        a[6] = (short)f2bu(f1.z * inv); a[7] = (short)f2bu(f1.w * inv);
        s16x8 b = *(const s16x8*)(bb + (size_t)brow * DD + c * 32 + q * 8);
        acc = __builtin_amdgcn_mfma_f32_16x16x32_bf16(a, b, acc, 0, 0, 0);
    }
    int cc = nt * 16 + r16;
    float bias = gb1[cc];
#pragma unroll
    for (int r = 0; r < 4; r++) {
        int row = mt * 16 + q * 4 + r;
        t1[(size_t)row * 1024 + cc] = f2b(fmaxf(acc[r] + bias, 0.f));
    }
}

// ---------------- FC2 MFMA ----------------
__global__ __launch_bounds__(256) void fc2_mfma(const bf16* __restrict__ t1,
                                                const bf16* __restrict__ gW2t,
                                                const float* __restrict__ gb2,
                                                float* __restrict__ out) {
    int wid = (blockIdx.x * 256 + threadIdx.x) >> 6;  // 64*8 waves
    int lane = threadIdx.x & 63;
    int mt = wid >> 3;
    int nt = wid & 7;
    int r16 = lane & 15;
    int q = lane >> 4;
    const short* ab = (const short*)t1;
    const short* bb = (const short*)gW2t;
    f32x4 acc = {0.f, 0.f, 0.f, 0.f};
    int arow = mt * 16 + r16;
    int brow = nt * 16 + r16;
#pragma unroll
    for (int c = 0; c < 32; c++) {
        s16x8 a = *(const s16x8*)(ab + (size_t)arow * 1024 + c * 32 + q * 8);
        s16x8 b = *(const s16x8*)(bb + (size_t)brow * 1024 + c * 32 + q * 8);
        acc = __builtin_amdgcn_mfma_f32_16x16x32_bf16(a, b, acc, 0, 0, 0);
    }
    int cc = nt * 16 + r16;
    float bias = gb2[cc];
#pragma unroll
    for (int r = 0; r < 4; r++) {
        int row = mt * 16 + q * 4 + r;
        out[(size_t)row * DD + cc] = acc[r] + bias;
    }
}

__global__ void sentinel_only(float* out, int hostcode) {
    if (threadIdx.x == 0 && blockIdx.x == 0) out[0] = (float)hostcode;
}

extern "C" void kernel_launch(void* const* d_in, const int* in_sizes, int n_in,
                              void* d_out, int out_size, void* d_ws, size_t ws_size,
                              hipStream_t stream) {
    float* out = (float*)d_out;

    static const int expect[15] = {3900000, 1600000, 50000, 9984, 128, 16384, 128,
                                   196608, 1536, 1536, 384, 131072, 1024, 131072, 128};
    int hostcode = 0;
    if (n_in != 15) hostcode = 21099;
    else for (int i = 0; i < 15; i++) if (in_sizes[i] != expect[i]) { hostcode = 21000 + i; break; }
    if (hostcode == 0 && out_size != GG * DD) hostcode = 35000;

    const float* x       = (const float*)d_in[0];
    const float* W1      = (const float*)d_in[3];
    const float* b1      = (const float*)d_in[4];
    const float* W2      = (const float*)d_in[5];
    const float* b2      = (const float*)d_in[6];
    const float* lin_w   = (const float*)d_in[7];
    const float* att_src = (const float*)d_in[8];
    const float* att_dst = (const float*)d_in[9];
    const float* conv_b  = (const float*)d_in[10];
    const float* gW1     = (const float*)d_in[11];
    const float* gb1     = (const float*)d_in[12];
    const float* gW2     = (const float*)d_in[13];
    const float* gb2     = (const float*)d_in[14];

    char* p = (char*)d_ws;
    auto alloc = [&](size_t bytes) { void* q = (void*)p; p += (bytes + 255) & ~(size_t)255; return q; };
    int*   ei32   = (int*)alloc((size_t)2 * EE * 4);
    int*   bat32  = (int*)alloc((size_t)NN * 4);
    bf16*  W1tb   = (bf16*)alloc((size_t)DD * K1P * 2);
    bf16*  W2tb   = (bf16*)alloc((size_t)DD * DD * 2);
    bf16*  hA     = (bf16*)alloc((size_t)NN * DD * 2);
    bf16*  hB     = (bf16*)alloc((size_t)NN * DD * 2);
    bf16*  Bt     = (bf16*)alloc((size_t)LL * DD * HD * 2);
    float* wsbuf  = (float*)alloc((size_t)LL * DD * HH * 4);
    float* wdbuf  = (float*)alloc((size_t)LL * DD * HH * 4);
    float* a_sA   = (float*)alloc((size_t)NN * HH * 4);
    float* a_dA   = (float*)alloc((size_t)NN * HH * 4);
    int*   deg    = (int*)alloc((size_t)NN * 4);
    int*   start  = (int*)alloc((size_t)(NN + 1) * 4);
    int*   cursor = (int*)alloc((size_t)NN * 4);
    int*   ssrc   = (int*)alloc((size_t)ET * 4);
    int*   bsum   = (int*)alloc((size_t)SB * 4);
    float* pooled = (float*)alloc((size_t)GG * DD * 4);
    int*   counts = (int*)alloc((size_t)GG * 4);
    bf16*  gW1t   = (bf16*)alloc((size_t)1024 * DD * 2);
    bf16*  gW2t   = (bf16*)alloc((size_t)DD * 1024 * 2);
    bf16*  t1buf  = (bf16*)alloc((size_t)GG * 1024 * 2);
    size_t need = (size_t)(p - (char*)d_ws);
    if (hostcode == 0 && ws_size < need) hostcode = 34000;

    if (hostcode != 0) {
        sentinel_only<<<1, 64, 0, stream>>>(out, hostcode);
        return;
    }

    // prep FIRST: zeroes counts/pooled and deg (before conv_all atomics)
    prep_misc<<<(PRE5 + 255) / 256, 256, 0, stream>>>(W1, W2, lin_w, att_src, att_dst, gW1, gW2,
                                                      W1tb, W2tb, Bt, wsbuf, wdbuf, gW1t, gW2t,
                                                      pooled, counts, deg);
    conv_all<<<(2 * EE + NN + 255) / 256, 256, 0, stream>>>(d_in[1], d_in[2], ei32, bat32,
                                                            deg, counts);

    mlp_fused<<<(NN / 16 * 64 + 255) / 256, 256, 0, stream>>>(x, W1tb, b1, W2tb, b2,
                                                              wsbuf, wdbuf, hA, a_sA, a_dA);

    block_sums<<<SB, 256, 0, stream>>>(deg, bsum);
    scan_final2<<<SB, 256, 0, stream>>>(deg, bsum, start, cursor);
    scatter_all<<<(NN + EE + 255) / 256, 256, 0, stream>>>(ei32, cursor, ssrc);

    bf16* hin = hA;
    bf16* hout = hB;
    for (int l = 0; l < LL; l++) {
        if (l > 0)   // layer 0's a_s/a_d comes fused from mlp_fused
            a_sd2<<<(NN + 255) / 256, 256, 0, stream>>>(hin, wsbuf + (size_t)l * DD * HH,
                                                        wdbuf + (size_t)l * DD * HH, a_sA, a_dA);
        agg_gemm<<<NN / 16, 1024, 0, stream>>>(start, ssrc, a_sA, a_dA, hin,
                                               Bt + (size_t)l * DD * HD, conv_b + l * DD, hout);
        bf16* tmp = hin; hin = hout; hout = tmp;
    }
    pool_accum2<<<(NN + 63) / 64, 256, 0, stream>>>(hin, bat32, pooled);
    fc1_mfma<<<(64 * 64) / 4, 256, 0, stream>>>(pooled, counts, gW1t, gb1, t1buf);
    fc2_mfma<<<(64 * 8) / 4, 256, 0, stream>>>(t1buf, gW2t, gb2, out);
}